// Round 6
// baseline (308.935 us; speedup 1.0000x reference)
//
#include <hip/hip_runtime.h>
#include <hip/hip_bf16.h>

// D = 16, N = 50000 nodes, E = 800000 edges.
//
//   out[n,o]  = bias[o] + sum_{u,v} x[n,u] * agg[n,v] * Wf[u,v,o]
//   agg[n,v]  = sum_{e: row_e=n} x[col_e,v]
//   Wf[u,v,o] = sum_w W_tp[u,v,w] * weight[o,w]
//
// Round-5 resubmit (GPU acquisition timed out; kernel never ran).
// Rounds 3/4 established atomic scatter = fabric-RMW bound at ~1.25 TB/s of
// per-atomic write traffic (43 us floor for 12.8M scalar atomics; packed v2
// atomics REGRESSED to 16B/op). So: build CSR on device (int atomics only),
// aggregate with read-only gathers, fused with the per-node bilinear.

#define D16 16
#define WF_STRIDE 260   // 260*4B = 1040B row stride: 16B-aligned, breaks bank aliasing
#define NT 4            // nodes per thread in bilinear phase
#define NBK 64          // nodes per block

typedef float v4f __attribute__((ext_vector_type(4)));

// ---- per-row degree count: 800k int atomics
__global__ __launch_bounds__(256) void count_k(const int* __restrict__ ei,
                                               int* __restrict__ cnt, int E) {
    int e = blockIdx.x * 256 + threadIdx.x;
    if (e < E) atomicAdd(&cnt[ei[e]], 1);
}

// ---- single-block exclusive prefix sum over N degree counts
__global__ __launch_bounds__(1024) void scan_k(const int* __restrict__ cnt,
                                               int* __restrict__ offs, int N) {
    __shared__ int part[1024];
    int t = threadIdx.x;
    int chunk = (N + 1023) >> 10;           // 49
    int lo = t * chunk, hi = lo + chunk;
    if (lo > N) lo = N;
    if (hi > N) hi = N;
    int s = 0;
    for (int i = lo; i < hi; ++i) s += cnt[i];
    part[t] = s;
    __syncthreads();
    for (int d = 1; d < 1024; d <<= 1) {    // Hillis-Steele inclusive scan
        int v = (t >= d) ? part[t - d] : 0;
        __syncthreads();
        part[t] += v;
        __syncthreads();
    }
    int base = (t == 0) ? 0 : part[t - 1];
    for (int i = lo; i < hi; ++i) { offs[i] = base; base += cnt[i]; }
}

// ---- scatter edge cols into CSR slots; offs[n] becomes END marker of node n
__global__ __launch_bounds__(256) void fill_k(const int* __restrict__ ei,
                                              int* __restrict__ offs,
                                              int* __restrict__ csr, int E) {
    int e = blockIdx.x * 256 + threadIdx.x;
    if (e < E) {
        int r = ei[e];
        int c = ei[E + e];
        int slot = atomicAdd(&offs[r], 1);
        csr[slot] = c;
    }
}

// ---- fused: gather-aggregate neighbors (read-only) + bilinear + linear + bias
__global__ __launch_bounds__(256) void fused_k(const float* __restrict__ x,
                                               const int* __restrict__ offs,
                                               const int* __restrict__ csr,
                                               const float* __restrict__ Wtp,
                                               const float* __restrict__ wgt,
                                               const float* __restrict__ bias,
                                               float* __restrict__ out, int N) {
    __shared__ float sWf[D16 * WF_STRIDE];  // 16.6 KB fused weight
    __shared__ float sx[NBK * D16];         // 4 KB
    __shared__ float sa[NBK * D16];         // 4 KB

    int t = threadIdx.x;

    // build fused weight: sWf[o*WF_STRIDE + u*16+v] = sum_w Wtp[(u*16+v)*16+w]*wgt[o*16+w]
    for (int i = t; i < D16 * WF_STRIDE; i += 256) {
        int o = i / WF_STRIDE, uv = i - o * WF_STRIDE;
        float acc = 0.f;
        if (uv < 256) {
#pragma unroll
            for (int w = 0; w < D16; ++w)
                acc = fmaf(Wtp[uv * D16 + w], wgt[o * D16 + w], acc);
        }
        sWf[i] = acc;
    }

    int nbase = blockIdx.x * NBK;
    const v4f* x4 = (const v4f*)x;

    // stage this block's x rows: NBK*4 = 256 float4s, one per thread
    {
        int g4 = nbase * 4 + t;
        v4f v = {0.f, 0.f, 0.f, 0.f};
        if (g4 < N * 4) v = x4[g4];
        ((v4f*)sx)[t] = v;
    }

    // gather-aggregate: 4 lanes per node, lane p sums features [4p,4p+4)
    {
        int nl = t >> 2, p = t & 3;
        int n = nbase + nl;
        v4f a = {0.f, 0.f, 0.f, 0.f};
        if (n < N) {
            int lo = (n == 0) ? 0 : offs[n - 1];
            int hi = offs[n];
            for (int j = lo; j < hi; ++j) {
                int c = csr[j];          // broadcast across the node's 4 lanes
                a += x4[c * 4 + p];      // 64B segment per node per iter
            }
        }
        ((v4f*)sa)[nl * 4 + p] = a;
    }
    __syncthreads();

    // bilinear: thread (gq,o) handles NT nodes; agg in regs, x via LDS broadcast
    int o = t & 15, gq = t >> 4;
    int nl0 = gq * NT;

    float av[NT][D16];
#pragma unroll
    for (int k = 0; k < NT; ++k)
#pragma unroll
        for (int i = 0; i < D16; ++i)
            av[k][i] = sa[(nl0 + k) * D16 + i];

    float b = bias[o];
    float acc[NT];
#pragma unroll
    for (int k = 0; k < NT; ++k) acc[k] = b;

    const float* wrow = &sWf[o * WF_STRIDE];
#pragma unroll
    for (int u = 0; u < D16; ++u) {
        float tu[NT] = {0.f, 0.f, 0.f, 0.f};
#pragma unroll
        for (int v = 0; v < D16; ++v) {            // consecutive v -> b128 LDS reads
            float wv = wrow[u * D16 + v];
#pragma unroll
            for (int k = 0; k < NT; ++k)
                tu[k] = fmaf(av[k][v], wv, tu[k]);
        }
#pragma unroll
        for (int k = 0; k < NT; ++k)
            acc[k] = fmaf(sx[(nl0 + k) * D16 + u], tu[k], acc[k]);  // LDS broadcast
    }

#pragma unroll
    for (int k = 0; k < NT; ++k) {
        int n = nbase + nl0 + k;
        if (n < N) out[n * D16 + o] = acc[k];
    }
}

extern "C" void kernel_launch(void* const* d_in, const int* in_sizes, int n_in,
                              void* d_out, int out_size, void* d_ws, size_t ws_size,
                              hipStream_t stream) {
    const float* x    = (const float*)d_in[0];
    const int*   ei   = (const int*)d_in[1];
    const float* Wtp  = (const float*)d_in[2];
    const float* wgt  = (const float*)d_in[3];
    const float* bias = (const float*)d_in[4];
    float* out = (float*)d_out;

    int N = in_sizes[0] / D16;   // 50000
    int E = in_sizes[1] / 2;     // 800000

    // workspace: cnt[N] | offs[N] | csr[E]  = 3.6 MB
    int* cnt  = (int*)d_ws;
    int* offs = cnt + N;
    int* csr  = offs + N;

    hipMemsetAsync(cnt, 0, (size_t)N * sizeof(int), stream);

    int eblocks = (E + 255) / 256;   // 3125
    count_k<<<eblocks, 256, 0, stream>>>(ei, cnt, E);
    scan_k<<<1, 1024, 0, stream>>>(cnt, offs, N);
    fill_k<<<eblocks, 256, 0, stream>>>(ei, offs, csr, E);

    int nblocks = (N + NBK - 1) / NBK;   // 782
    fused_k<<<nblocks, 256, 0, stream>>>(x, offs, csr, Wtp, wgt, bias, out, N);
}

// Round 14
// 168.489 us; speedup vs baseline: 1.8336x; 1.8336x over previous
//
#include <hip/hip_runtime.h>
#include <hip/hip_bf16.h>

// D = 16, N = 50000 nodes, E = 800000 edges.
//
//   out[n,o]  = bias[o] + sum_{u,v} x[n,u] * agg[n,v] * Wf[u,v,o]
//   agg[n,v]  = sum_{e: row_e=n} x[col_e,v]
//   Wf[u,v,o] = sum_w W_tp[u,v,w] * weight[o,w]
//
// Round-14 resubmit (rounds 11/12/13 hit GPU acquisition timeouts; never
// ran). Cooperative launch ABANDONED — not graph-capturable on this harness
// (round 8: silent no-op; round 10: capture invalidated -> container abort).
// Capture-safe 3-dispatch structure with proven components:
//   - scatter_k: round-3-proven scalar 4B atomics, fabric-RMW bound
//     (51.2 MB at ~1.25 TB/s = 43 us; packed atomics regress 2x, round 4).
//   - bilin_k: NT=2 register-blocked bilinear with fuse_w folded in
//     (untimed so far; this round measures it cleanly).

#define D16 16
#define WF_STRIDE 260   // 260*4B row stride: 16B-aligned; 2-way bank alias (free, m136)
#define NT 2            // nodes per thread in bilinear
#define TILE_NODES 32   // NT * (256/16)

// ---- scatter: agg[row_e][v] += x[col_e][v], one thread per (edge, feature)
__global__ __launch_bounds__(256) void scatter_k(const int* __restrict__ ei,
                                                 const float* __restrict__ x,
                                                 float* __restrict__ agg,
                                                 int E) {
    int t = blockIdx.x * 256 + threadIdx.x;
    if (t >= E * D16) return;
    int e = t >> 4;
    int v = t & 15;
    int r = ei[e];        // broadcast across the edge's 16 lanes
    int c = ei[E + e];
    unsafeAtomicAdd(&agg[r * D16 + v], x[c * D16 + v]);
}

// ---- fused: build Wf in LDS + per-node bilinear + linear + bias, NT nodes/thread
__global__ __launch_bounds__(256) void bilin_k(const float* __restrict__ x,
                                               const float* __restrict__ agg,
                                               const float* __restrict__ Wtp,
                                               const float* __restrict__ wgt,
                                               const float* __restrict__ bias,
                                               float* __restrict__ out, int N) {
    __shared__ float sWf[D16 * WF_STRIDE];   // 16.6 KB
    __shared__ float sx[TILE_NODES * D16];   // 2 KB
    __shared__ float sa[TILE_NODES * D16];   // 2 KB

    int t = threadIdx.x;

    // build fused weight: sWf[o*WF_STRIDE + u*16+v] = sum_w Wtp[(u*16+v)*16+w]*wgt[o*16+w]
    for (int i = t; i < D16 * WF_STRIDE; i += 256) {
        int o = i / WF_STRIDE, uv = i - o * WF_STRIDE;
        float acc = 0.f;
        if (uv < 256) {
#pragma unroll
            for (int w = 0; w < D16; ++w)
                acc = fmaf(Wtp[uv * D16 + w], wgt[o * D16 + w], acc);
        }
        sWf[i] = acc;
    }

    int total = N * D16;
    int nbase = blockIdx.x * TILE_NODES;
#pragma unroll
    for (int k = 0; k < 2; ++k) {            // stage 512 floats each, coalesced
        int i = k * 256 + t;
        int g = nbase * D16 + i;
        bool ok = g < total;
        sx[i] = ok ? x[g] : 0.f;
        sa[i] = ok ? agg[g] : 0.f;
    }
    __syncthreads();

    int o = t & 15, gq = t >> 4;
    int nl0 = gq * NT;

    float av[NT][D16], xv[NT][D16];
#pragma unroll
    for (int k = 0; k < NT; ++k)
#pragma unroll
        for (int i = 0; i < D16; ++i) {
            av[k][i] = sa[(nl0 + k) * D16 + i];
            xv[k][i] = sx[(nl0 + k) * D16 + i];
        }

    float acc[NT];
    float b = bias[o];
#pragma unroll
    for (int k = 0; k < NT; ++k) acc[k] = b;

    const float* wrow = &sWf[o * WF_STRIDE];
#pragma unroll
    for (int u = 0; u < D16; ++u) {
        float tu[NT] = {0.f, 0.f};
#pragma unroll
        for (int v = 0; v < D16; ++v) {      // consecutive v -> b128 LDS reads
            float wv = wrow[u * D16 + v];
#pragma unroll
            for (int k = 0; k < NT; ++k)
                tu[k] = fmaf(av[k][v], wv, tu[k]);
        }
#pragma unroll
        for (int k = 0; k < NT; ++k)
            acc[k] = fmaf(xv[k][u], tu[k], acc[k]);
    }

#pragma unroll
    for (int k = 0; k < NT; ++k) {
        int n = nbase + nl0 + k;
        if (n < N) out[n * D16 + o] = acc[k];
    }
}

extern "C" void kernel_launch(void* const* d_in, const int* in_sizes, int n_in,
                              void* d_out, int out_size, void* d_ws, size_t ws_size,
                              hipStream_t stream) {
    const float* x    = (const float*)d_in[0];
    const int*   ei   = (const int*)d_in[1];
    const float* Wtp  = (const float*)d_in[2];
    const float* wgt  = (const float*)d_in[3];
    const float* bias = (const float*)d_in[4];
    float* out = (float*)d_out;

    int N = in_sizes[0] / D16;   // 50000
    int E = in_sizes[1] / 2;     // 800000

    float* agg = (float*)d_ws;   // N*16 floats

    // ws is poisoned 0xAA before every launch -> zero the accumulator
    hipMemsetAsync(agg, 0, (size_t)N * D16 * sizeof(float), stream);

    int sthreads = E * D16;      // 12.8M
    scatter_k<<<(sthreads + 255) / 256, 256, 0, stream>>>(ei, x, agg, E);

    int nblocks = (N + TILE_NODES - 1) / TILE_NODES;   // 1563
    bilin_k<<<nblocks, 256, 0, stream>>>(x, agg, Wtp, wgt, bias, out, N);
}

// Round 18
// 133.377 us; speedup vs baseline: 2.3162x; 1.2633x over previous
//
#include <hip/hip_runtime.h>
#include <hip/hip_bf16.h>

// D = 16, N = 50000 nodes, E = 800000 edges.
//
//   out[n,o]  = bias[o] + sum_{u,v} x[n,u] * agg[n,v] * Wf[u,v,o]
//   agg[n,v]  = sum_{e: row_e=n} x[col_e,v]
//   Wf[u,v,o] = sum_w W_tp[u,v,w] * weight[o,w]
//
// Round-18 resubmit (rounds 15/16/17 hit GPU acquisition timeouts; never
// ran). Round-14 profiled the bilinear: 65 us, latency-bound (VALUBusy 17%,
// occupancy 9%) — the per-block sWf rebuild from Wtp/wgt (544 scalar global
// loads/thread x 1563 blocks) was the cost, exactly as in round-6's fused_k.
// Round-3's variant that LOADED a prebuilt Wf stayed <43 us. Fix:
//   - prep_k: ONE dispatch that zeroes agg (grid-stride) AND builds the
//     4096-float Wf into ws (blocks 0..15). Replaces memset + per-block build.
//   - scatter_k: unchanged (round-3-proven 43 us fabric-RMW floor;
//     WRITE_SIZE 50,001 KB signature).
//   - bilin_k: loads prebuilt Wf with 4 coalesced float4 reads/thread,
//     then the NT=2 register-blocked compute (unchanged).

#define D16 16
#define WF_STRIDE 260   // 260*4B row stride: 16B-aligned; 2-way bank alias (free)
#define NT 2            // nodes per thread in bilinear
#define TILE_NODES 32   // NT * (256/16)

typedef float v4f __attribute__((ext_vector_type(4)));

// ---- prep: zero agg + build Wf[o*256 + uv] = sum_w Wtp[uv*16+w] * wgt[o*16+w]
__global__ __launch_bounds__(256) void prep_k(const float* __restrict__ Wtp,
                                              const float* __restrict__ wgt,
                                              float* __restrict__ agg,
                                              float* __restrict__ Wf,
                                              int total) {
    int bid = blockIdx.x, t = threadIdx.x;
    if (bid < 16) {                       // 16*256 = 4096 Wf entries
        int idx = bid * 256 + t;
        int o = idx >> 8, uv = idx & 255;
        float acc = 0.f;
#pragma unroll
        for (int w = 0; w < D16; ++w)
            acc = fmaf(Wtp[uv * D16 + w], wgt[o * D16 + w], acc);
        Wf[idx] = acc;
    }
    for (int i = bid * 256 + t; i < total; i += gridDim.x * 256)
        agg[i] = 0.f;
}

// ---- scatter: agg[row_e][v] += x[col_e][v], one thread per (edge, feature)
__global__ __launch_bounds__(256) void scatter_k(const int* __restrict__ ei,
                                                 const float* __restrict__ x,
                                                 float* __restrict__ agg,
                                                 int E) {
    int t = blockIdx.x * 256 + threadIdx.x;
    if (t >= E * D16) return;
    int e = t >> 4;
    int v = t & 15;
    int r = ei[e];        // broadcast across the edge's 16 lanes
    int c = ei[E + e];
    unsafeAtomicAdd(&agg[r * D16 + v], x[c * D16 + v]);
}

// ---- bilinear: load prebuilt Wf (coalesced) + NT=2 register-blocked compute
__global__ __launch_bounds__(256) void bilin_k(const float* __restrict__ x,
                                               const float* __restrict__ agg,
                                               const float* __restrict__ Wf,
                                               const float* __restrict__ bias,
                                               float* __restrict__ out, int N) {
    __shared__ float sWf[D16 * WF_STRIDE];   // 16.6 KB
    __shared__ float sx[TILE_NODES * D16];   // 2 KB
    __shared__ float sa[TILE_NODES * D16];   // 2 KB

    int t = threadIdx.x;

    // load prebuilt Wf: 4096 floats = 1024 float4s, coalesced, pad into sWf
    const v4f* w4 = (const v4f*)Wf;
    for (int i = t; i < 1024; i += 256) {
        v4f v = w4[i];
        int fi = i << 2;
        int o = fi >> 8, uv = fi & 255;      // uv multiple of 4; 260%4==0 -> 16B aligned
        *(v4f*)&sWf[o * WF_STRIDE + uv] = v;
    }

    int total = N * D16;
    int nbase = blockIdx.x * TILE_NODES;
#pragma unroll
    for (int k = 0; k < 2; ++k) {            // stage 512 floats each, coalesced
        int i = k * 256 + t;
        int g = nbase * D16 + i;
        bool ok = g < total;
        sx[i] = ok ? x[g] : 0.f;
        sa[i] = ok ? agg[g] : 0.f;
    }
    __syncthreads();

    int o = t & 15, gq = t >> 4;
    int nl0 = gq * NT;

    float av[NT][D16], xv[NT][D16];
#pragma unroll
    for (int k = 0; k < NT; ++k)
#pragma unroll
        for (int i = 0; i < D16; ++i) {
            av[k][i] = sa[(nl0 + k) * D16 + i];
            xv[k][i] = sx[(nl0 + k) * D16 + i];
        }

    float acc[NT];
    float b = bias[o];
#pragma unroll
    for (int k = 0; k < NT; ++k) acc[k] = b;

    const float* wrow = &sWf[o * WF_STRIDE];
#pragma unroll
    for (int u = 0; u < D16; ++u) {
        float tu[NT] = {0.f, 0.f};
#pragma unroll
        for (int v = 0; v < D16; ++v) {      // consecutive v -> b128 LDS reads
            float wv = wrow[u * D16 + v];
#pragma unroll
            for (int k = 0; k < NT; ++k)
                tu[k] = fmaf(av[k][v], wv, tu[k]);
        }
#pragma unroll
        for (int k = 0; k < NT; ++k)
            acc[k] = fmaf(xv[k][u], tu[k], acc[k]);
    }

#pragma unroll
    for (int k = 0; k < NT; ++k) {
        int n = nbase + nl0 + k;
        if (n < N) out[n * D16 + o] = acc[k];
    }
}

extern "C" void kernel_launch(void* const* d_in, const int* in_sizes, int n_in,
                              void* d_out, int out_size, void* d_ws, size_t ws_size,
                              hipStream_t stream) {
    const float* x    = (const float*)d_in[0];
    const int*   ei   = (const int*)d_in[1];
    const float* Wtp  = (const float*)d_in[2];
    const float* wgt  = (const float*)d_in[3];
    const float* bias = (const float*)d_in[4];
    float* out = (float*)d_out;

    int N = in_sizes[0] / D16;   // 50000
    int E = in_sizes[1] / 2;     // 800000

    float* agg = (float*)d_ws;                   // N*16 floats
    float* Wf  = agg + (size_t)N * D16;          // 4096 floats [o][uv]

    int total = N * D16;
    prep_k<<<784, 256, 0, stream>>>(Wtp, wgt, agg, Wf, total);

    int sthreads = E * D16;      // 12.8M
    scatter_k<<<(sthreads + 255) / 256, 256, 0, stream>>>(ei, x, agg, E);

    int nblocks = (N + TILE_NODES - 1) / TILE_NODES;   // 1563
    bilin_k<<<nblocks, 256, 0, stream>>>(x, agg, Wf, bias, out, N);
}